// Round 8
// baseline (383.222 us; speedup 1.0000x reference)
//
#include <hip/hip_runtime.h>
#include <hip/hip_fp16.h>

namespace {
constexpr int CS = 16;        // channels
constexpr int XS = 8, YS = 8, US = 256, VS = 256;
constexpr int CH_STRIDE = XS * YS * US * VS;               // 4,194,304 voxels
constexpr size_t NVOX = (size_t)CH_STRIDE;
constexpr size_t ATLAS_HALFS = NVOX * CS;                  // 67,108,864 halfs = 128 MiB
constexpr size_t SINGLE_BYTES = ATLAS_HALFS * 2;           // 128 MiB
constexpr int NB = 4;                                      // u-slice buckets
constexpr int USH = 6;                                     // iu >> 6 -> 0..3

// ---- Kernel 1: repack [C,X,Y,U,V] f32 -> fp16 atlas [X,Y,U,V,C] -----------
__global__ __launch_bounds__(256) void transpose_h_kernel(
    const float* __restrict__ inp, __half* __restrict__ ws)
{
    __shared__ float lds[CS][257];
    size_t base = (size_t)blockIdx.x * 256;
    #pragma unroll
    for (int c = 0; c < CS; ++c)
        lds[c][threadIdx.x] = inp[(size_t)c * CH_STRIDE + base + threadIdx.x];
    __syncthreads();
    size_t obase = base * CS;
    #pragma unroll
    for (int it = 0; it < 2; ++it) {
        int flat0 = (it * 256 + threadIdx.x) * 8;
        uint4 pk;
        uint* pw = &pk.x;
        #pragma unroll
        for (int j = 0; j < 4; ++j) {
            int f0 = flat0 + j * 2, f1 = f0 + 1;
            __half2 h = __floats2half2_rn(lds[f0 & 15][f0 >> 4],
                                          lds[f1 & 15][f1 >> 4]);
            pw[j] = *reinterpret_cast<uint*>(&h);
        }
        *reinterpret_cast<uint4*>(ws + obase + flat0) = pk;
    }
}

// ---- helpers ---------------------------------------------------------------
__device__ __forceinline__ int bucket_of(const float4& g) {
    float c2 = (g.z + 1.0f) * 0.5f * (US - 1);
    int iu = min(max((int)floorf(c2), 0), US - 1);
    return iu >> USH;
}

// Full 16-corner fp16 gather for one point; a[16] out.
__device__ __forceinline__ void gather_point(
    const __half* __restrict__ tin, const float4& g, float* a)
{
    float c0 = (g.x + 1.0f) * 0.5f * (XS - 1);
    float c1 = (g.y + 1.0f) * 0.5f * (YS - 1);
    float c2 = (g.z + 1.0f) * 0.5f * (US - 1);
    float c3 = (g.w + 1.0f) * 0.5f * (VS - 1);
    float f0 = floorf(c0), f1 = floorf(c1), f2 = floorf(c2), f3 = floorf(c3);
    int i0 = (int)f0, i1 = (int)f1, i2 = (int)f2, i3 = (int)f3;
    float t0 = c0 - f0, t1 = c1 - f1, t2 = c2 - f2, t3 = c3 - f3;
    float w0[2], w1[2], w2[2], w3[2];
    int   q0[2], q1[2], q2[2], q3[2];
    #pragma unroll
    for (int b = 0; b < 2; ++b) {
        int j;
        j = i0 + b; w0[b] = (b ? t0 : 1.0f - t0) * ((j >= 0 && j < XS) ? 1.0f : 0.0f); q0[b] = min(max(j, 0), XS - 1);
        j = i1 + b; w1[b] = (b ? t1 : 1.0f - t1) * ((j >= 0 && j < YS) ? 1.0f : 0.0f); q1[b] = min(max(j, 0), YS - 1);
        j = i2 + b; w2[b] = (b ? t2 : 1.0f - t2) * ((j >= 0 && j < US) ? 1.0f : 0.0f); q2[b] = min(max(j, 0), US - 1);
        j = i3 + b; w3[b] = (b ? t3 : 1.0f - t3) * ((j >= 0 && j < VS) ? 1.0f : 0.0f); q3[b] = min(max(j, 0), VS - 1);
    }
    #pragma unroll
    for (int i = 0; i < 16; ++i) a[i] = 0.0f;
    #pragma unroll
    for (int bx = 0; bx < 2; ++bx)
    #pragma unroll
    for (int by = 0; by < 2; ++by) {
        int   xy  = (q0[bx] * YS + q1[by]) << 16;
        float wxy = w0[bx] * w1[by];
        #pragma unroll
        for (int bu = 0; bu < 2; ++bu) {
            int   xyu  = xy + (q2[bu] << 8);
            float wxyu = wxy * w2[bu];
            #pragma unroll
            for (int bv = 0; bv < 2; ++bv) {
                int   vox = xyu + q3[bv];
                float w   = wxyu * w3[bv];
                const uint4* cp = reinterpret_cast<const uint4*>(tin) + (size_t)vox * 2;
                uint4 r0 = cp[0], r1 = cp[1];
                uint rr[8] = {r0.x, r0.y, r0.z, r0.w, r1.x, r1.y, r1.z, r1.w};
                #pragma unroll
                for (int j = 0; j < 8; ++j) {
                    float2 f = __half22float2(*reinterpret_cast<const __half2*>(&rr[j]));
                    a[2*j]     = fmaf(w, f.x, a[2*j]);
                    a[2*j + 1] = fmaf(w, f.y, a[2*j + 1]);
                }
            }
        }
    }
}

// ---- Kernel 2: per-block bucket counts (no global atomics) -----------------
__global__ __launch_bounds__(256) void blockcount_kernel(
    const float* __restrict__ grid, int* __restrict__ bc, int P)
{
    __shared__ int cnt[NB];
    if (threadIdx.x < NB) cnt[threadIdx.x] = 0;
    __syncthreads();
    int p = blockIdx.x * 256 + threadIdx.x;
    if (p < P) {
        float4 g = reinterpret_cast<const float4*>(grid)[p];
        atomicAdd(&cnt[bucket_of(g)], 1);
    }
    __syncthreads();
    if (threadIdx.x < NB) bc[blockIdx.x * NB + threadIdx.x] = cnt[threadIdx.x];
}

// ---- Kernel 3: scan block counts -> per-block bases + bucket offsets -------
__global__ __launch_bounds__(256) void scan_kernel(
    const int* __restrict__ bc, int* __restrict__ base, int* __restrict__ off, int T)
{
    __shared__ int part[256][NB];
    __shared__ int boff[NB + 1];
    int t = threadIdx.x;
    int chunk = (T + 255) / 256;
    int s[NB];
    #pragma unroll
    for (int b = 0; b < NB; ++b) s[b] = 0;
    for (int i = 0; i < chunk; ++i) {
        int blk = t * chunk + i;
        if (blk < T)
            #pragma unroll
            for (int b = 0; b < NB; ++b) s[b] += bc[blk * NB + b];
    }
    #pragma unroll
    for (int b = 0; b < NB; ++b) part[t][b] = s[b];
    __syncthreads();
    for (int o = 1; o < 256; o <<= 1) {               // inclusive scan over t
        int v[NB];
        #pragma unroll
        for (int b = 0; b < NB; ++b) v[b] = (t >= o) ? part[t - o][b] : 0;
        __syncthreads();
        #pragma unroll
        for (int b = 0; b < NB; ++b) part[t][b] += v[b];
        __syncthreads();
    }
    if (t == 0) {
        boff[0] = 0;
        for (int b = 0; b < NB; ++b) boff[b + 1] = boff[b] + part[255][b];
        for (int b = 0; b <= NB; ++b) off[b] = boff[b];
    }
    __syncthreads();
    int run[NB];
    #pragma unroll
    for (int b = 0; b < NB; ++b) run[b] = boff[b] + part[t][b] - s[b];  // exclusive
    for (int i = 0; i < chunk; ++i) {
        int blk = t * chunk + i;
        if (blk < T)
            #pragma unroll
            for (int b = 0; b < NB; ++b) { base[blk * NB + b] = run[b]; run[b] += bc[blk * NB + b]; }
    }
}

// ---- Kernel 4: scatter points into bucket order ----------------------------
__global__ __launch_bounds__(256) void scatter_kernel(
    const float* __restrict__ grid, const int* __restrict__ base,
    float4* __restrict__ sg, int* __restrict__ inv, int P)
{
    __shared__ int rank[NB];
    if (threadIdx.x < NB) rank[threadIdx.x] = 0;
    __syncthreads();
    int p = blockIdx.x * 256 + threadIdx.x;
    if (p >= P) return;
    float4 g = reinterpret_cast<const float4*>(grid)[p];
    int b = bucket_of(g);
    int r = atomicAdd(&rank[b], 1);                   // LDS atomic, block-local
    int s = base[blockIdx.x * NB + b] + r;
    sg[s] = g;
    inv[p] = s;
}

// ---- Kernel 5 (x4 launches): gather one bucket; write per-slot -------------
__global__ __launch_bounds__(256) void gather_bucket_kernel(
    const __half* __restrict__ tin, const float4* __restrict__ sg,
    float4* __restrict__ ws2, const int* __restrict__ off, int k)
{
    int lo = off[k], hi = off[k + 1];
    for (int s = lo + blockIdx.x * 256 + threadIdx.x; s < hi; s += gridDim.x * 256) {
        float4 g = sg[s];
        float a[16];
        gather_point(tin, g, a);
        float4* d = ws2 + (size_t)s * 4;
        d[0] = make_float4(a[0], a[1], a[2], a[3]);
        d[1] = make_float4(a[4], a[5], a[6], a[7]);
        d[2] = make_float4(a[8], a[9], a[10], a[11]);
        d[3] = make_float4(a[12], a[13], a[14], a[15]);
    }
}

// ---- Kernel 6: unpermute slots -> [C,P] output -----------------------------
__global__ __launch_bounds__(256) void unpermute_kernel(
    const float4* __restrict__ ws2, const int* __restrict__ inv,
    float* __restrict__ out, int P)
{
    int p = blockIdx.x * 256 + threadIdx.x;
    if (p >= P) return;
    int s = inv[p];
    const float4* src = ws2 + (size_t)s * 4;          // one 64B line per point
    float4 r0 = src[0], r1 = src[1], r2 = src[2], r3 = src[3];
    float r[16] = {r0.x,r0.y,r0.z,r0.w, r1.x,r1.y,r1.z,r1.w,
                   r2.x,r2.y,r2.z,r2.w, r3.x,r3.y,r3.z,r3.w};
    #pragma unroll
    for (int c = 0; c < CS; ++c)
        __builtin_nontemporal_store(r[c], &out[(size_t)c * P + p]);
}

// ---- R6 direct gather (fallback when ws fits atlas only) -------------------
__global__ __launch_bounds__(256) void gather_h_kernel(
    const __half* __restrict__ tin, const float* __restrict__ grid,
    float* __restrict__ out, int P)
{
    int p = blockIdx.x * 256 + threadIdx.x;
    if (p >= P) return;
    float4 g = reinterpret_cast<const float4*>(grid)[p];
    float a[16];
    gather_point(tin, g, a);
    #pragma unroll
    for (int c = 0; c < CS; ++c)
        __builtin_nontemporal_store(a[c], &out[(size_t)c * P + p]);
}

// ---- Last-resort fallback (no ws) ------------------------------------------
__global__ __launch_bounds__(256) void gs4d_fallback(
    const float* __restrict__ inp, const float* __restrict__ grid,
    float* __restrict__ out, int P)
{
    int p = blockIdx.x * 256 + threadIdx.x;
    if (p >= P) return;
    int c = blockIdx.y;
    float4 g = reinterpret_cast<const float4*>(grid)[p];
    float c0 = (g.x + 1.0f) * 0.5f * (XS - 1);
    float c1 = (g.y + 1.0f) * 0.5f * (YS - 1);
    float c2 = (g.z + 1.0f) * 0.5f * (US - 1);
    float c3 = (g.w + 1.0f) * 0.5f * (VS - 1);
    float f0 = floorf(c0), f1 = floorf(c1), f2 = floorf(c2), f3 = floorf(c3);
    int i0 = (int)f0, i1 = (int)f1, i2 = (int)f2, i3 = (int)f3;
    float t0 = c0 - f0, t1 = c1 - f1, t2 = c2 - f2, t3 = c3 - f3;
    float w0[2], w1[2], w2[2], w3[2];
    int   q0[2], q1[2], q2[2], q3[2];
    #pragma unroll
    for (int b = 0; b < 2; ++b) {
        int j;
        j = i0 + b; w0[b] = (b ? t0 : 1.0f - t0) * ((j >= 0 && j < XS) ? 1.0f : 0.0f); q0[b] = min(max(j, 0), XS - 1);
        j = i1 + b; w1[b] = (b ? t1 : 1.0f - t1) * ((j >= 0 && j < YS) ? 1.0f : 0.0f); q1[b] = min(max(j, 0), YS - 1);
        j = i2 + b; w2[b] = (b ? t2 : 1.0f - t2) * ((j >= 0 && j < US) ? 1.0f : 0.0f); q2[b] = min(max(j, 0), US - 1);
        j = i3 + b; w3[b] = (b ? t3 : 1.0f - t3) * ((j >= 0 && j < VS) ? 1.0f : 0.0f); q3[b] = min(max(j, 0), VS - 1);
    }
    const float* ip = inp + (size_t)c * CH_STRIDE;
    float acc = 0.0f;
    #pragma unroll
    for (int bx = 0; bx < 2; ++bx)
    #pragma unroll
    for (int by = 0; by < 2; ++by)
    #pragma unroll
    for (int bu = 0; bu < 2; ++bu)
    #pragma unroll
    for (int bv = 0; bv < 2; ++bv) {
        int idx = ((q0[bx] * YS + q1[by]) * US + q2[bu]) * VS + q3[bv];
        acc = fmaf(w0[bx] * w1[by] * w2[bu] * w3[bv], ip[idx], acc);
    }
    __builtin_nontemporal_store(acc, &out[(size_t)c * P + p]);
}
} // anonymous namespace

extern "C" void kernel_launch(void* const* d_in, const int* in_sizes, int n_in,
                              void* d_out, int out_size, void* d_ws, size_t ws_size,
                              hipStream_t stream) {
    const float* inp  = (const float*)d_in[0];   // [1,16,8,8,256,256] f32
    const float* grid = (const float*)d_in[1];   // [1,P,4] f32
    float* out = (float*)d_out;                  // [1,16,P] f32
    int P = in_sizes[1] / 4;
    int pblocks = (P + 255) / 256;

    // ws float layout: [atlas fp16][sortedgrid 4P][ws2 16P][inv P][bc][base][off]
    size_t f_atlas  = ATLAS_HALFS / 2;
    size_t f_sorted = (size_t)P * 4;
    size_t f_ws2    = (size_t)P * 16;
    size_t f_inv    = (size_t)P;
    size_t f_bc     = (size_t)pblocks * NB;
    size_t f_base   = (size_t)pblocks * NB;
    size_t need = (f_atlas + f_sorted + f_ws2 + f_inv + f_bc + f_base + NB + 8) * 4;

    if (ws_size >= need) {
        __half* atlas      = (__half*)d_ws;
        float*  ws0        = (float*)d_ws;
        float4* sortedgrid = (float4*)(ws0 + f_atlas);
        float4* ws2        = (float4*)(ws0 + f_atlas + f_sorted);
        int*    inv        = (int*)  (ws0 + f_atlas + f_sorted + f_ws2);
        int*    bc         = inv + f_inv;
        int*    base       = bc + f_bc;
        int*    off        = base + f_base;

        transpose_h_kernel<<<CH_STRIDE / 256, 256, 0, stream>>>(inp, atlas);
        blockcount_kernel<<<pblocks, 256, 0, stream>>>(grid, bc, P);
        scan_kernel<<<1, 256, 0, stream>>>(bc, base, off, pblocks);
        scatter_kernel<<<pblocks, 256, 0, stream>>>(grid, base, sortedgrid, inv, P);
        for (int k = 0; k < NB; ++k)
            gather_bucket_kernel<<<1024, 256, 0, stream>>>(atlas, sortedgrid, ws2, off, k);
        unpermute_kernel<<<pblocks, 256, 0, stream>>>(ws2, inv, out, P);
    } else if (ws_size >= SINGLE_BYTES) {
        __half* ws = (__half*)d_ws;
        transpose_h_kernel<<<CH_STRIDE / 256, 256, 0, stream>>>(inp, ws);
        gather_h_kernel<<<pblocks, 256, 0, stream>>>(ws, grid, out, P);
    } else {
        dim3 blocks(pblocks, CS);
        gs4d_fallback<<<blocks, 256, 0, stream>>>(inp, grid, out, P);
    }
}

// Round 9
// 266.344 us; speedup vs baseline: 1.4388x; 1.4388x over previous
//
#include <hip/hip_runtime.h>
#include <hip/hip_fp16.h>

namespace {
constexpr int CS = 16;        // channels
constexpr int XS = 8, YS = 8, US = 256, VS = 256;
constexpr int CH_STRIDE = XS * YS * US * VS;               // 4,194,304 voxels
constexpr size_t ATLAS_HALFS = (size_t)CH_STRIDE * CS;     // 128 MiB fp16 atlas
constexpr size_t SINGLE_BYTES = ATLAS_HALFS * 2;

// ---- Kernel 1: repack [C,X,Y,U,V] f32 -> fp16 atlas [X,Y,U,V,C] -----------
// 384 MB of sequential traffic; measured at the ~6.1 TB/s ceiling (63 us).
__global__ __launch_bounds__(256) void transpose_h_kernel(
    const float* __restrict__ inp, __half* __restrict__ ws)
{
    __shared__ float lds[CS][257];                 // +1 pad: no bank conflicts
    size_t base = (size_t)blockIdx.x * 256;        // 256 consecutive voxels
    #pragma unroll
    for (int c = 0; c < CS; ++c)                   // coalesced 4B reads per c
        lds[c][threadIdx.x] = inp[(size_t)c * CH_STRIDE + base + threadIdx.x];
    __syncthreads();
    size_t obase = base * CS;                      // in halfs
    #pragma unroll
    for (int it = 0; it < 2; ++it) {
        int flat0 = (it * 256 + threadIdx.x) * 8;  // 8 halfs (16 B) per store
        uint4 pk;
        uint* pw = &pk.x;
        #pragma unroll
        for (int j = 0; j < 4; ++j) {
            int f0 = flat0 + j * 2, f1 = f0 + 1;
            __half2 h = __floats2half2_rn(lds[f0 & 15][f0 >> 4],
                                          lds[f1 & 15][f1 >> 4]);
            pw[j] = *reinterpret_cast<uint*>(&h);
        }
        *reinterpret_cast<uint4*>(ws + obase + flat0) = pk;
    }
}

// ---- Kernel 2: gather from fp16 [X,Y,U,V,C]; 1 thread = 1 point, 16 ch ----
// ~12 distinct 64B line-touches/point at the measured ~47 G lines/s random
// touch ceiling (invariant to HBM-vs-L3 source per R5/R7/R8 probes): ~203 us.
__global__ __launch_bounds__(256) void gather_h_kernel(
    const __half* __restrict__ tin, const float* __restrict__ grid,
    float* __restrict__ out, int P)
{
    int p = blockIdx.x * 256 + threadIdx.x;
    if (p >= P) return;

    float4 g = reinterpret_cast<const float4*>(grid)[p];

    float c0 = (g.x + 1.0f) * 0.5f * (XS - 1);
    float c1 = (g.y + 1.0f) * 0.5f * (YS - 1);
    float c2 = (g.z + 1.0f) * 0.5f * (US - 1);
    float c3 = (g.w + 1.0f) * 0.5f * (VS - 1);

    float f0 = floorf(c0), f1 = floorf(c1), f2 = floorf(c2), f3 = floorf(c3);
    int i0 = (int)f0, i1 = (int)f1, i2 = (int)f2, i3 = (int)f3;
    float t0 = c0 - f0, t1 = c1 - f1, t2 = c2 - f2, t3 = c3 - f3;

    float w0[2], w1[2], w2[2], w3[2];
    int   q0[2], q1[2], q2[2], q3[2];
    #pragma unroll
    for (int b = 0; b < 2; ++b) {
        int j;
        j = i0 + b; w0[b] = (b ? t0 : 1.0f - t0) * ((j >= 0 && j < XS) ? 1.0f : 0.0f); q0[b] = min(max(j, 0), XS - 1);
        j = i1 + b; w1[b] = (b ? t1 : 1.0f - t1) * ((j >= 0 && j < YS) ? 1.0f : 0.0f); q1[b] = min(max(j, 0), YS - 1);
        j = i2 + b; w2[b] = (b ? t2 : 1.0f - t2) * ((j >= 0 && j < US) ? 1.0f : 0.0f); q2[b] = min(max(j, 0), US - 1);
        j = i3 + b; w3[b] = (b ? t3 : 1.0f - t3) * ((j >= 0 && j < VS) ? 1.0f : 0.0f); q3[b] = min(max(j, 0), VS - 1);
    }

    float a[16];
    #pragma unroll
    for (int i = 0; i < 16; ++i) a[i] = 0.0f;

    #pragma unroll
    for (int bx = 0; bx < 2; ++bx)
    #pragma unroll
    for (int by = 0; by < 2; ++by) {
        int   xy  = (q0[bx] * YS + q1[by]) << 16;           // * US*VS
        float wxy = w0[bx] * w1[by];
        #pragma unroll
        for (int bu = 0; bu < 2; ++bu) {
            int   xyu  = xy + (q2[bu] << 8);                // * VS
            float wxyu = wxy * w2[bu];
            #pragma unroll
            for (int bv = 0; bv < 2; ++bv) {
                int   vox = xyu + q3[bv];
                float w   = wxyu * w3[bv];
                const uint4* cp = reinterpret_cast<const uint4*>(tin) + (size_t)vox * 2;
                uint4 r0 = cp[0], r1 = cp[1];               // 16 halfs = 32 B
                uint rr[8] = {r0.x, r0.y, r0.z, r0.w, r1.x, r1.y, r1.z, r1.w};
                #pragma unroll
                for (int j = 0; j < 8; ++j) {
                    float2 f = __half22float2(*reinterpret_cast<const __half2*>(&rr[j]));
                    a[2*j]     = fmaf(w, f.x, a[2*j]);
                    a[2*j + 1] = fmaf(w, f.y, a[2*j + 1]);
                }
            }
        }
    }

    #pragma unroll
    for (int c = 0; c < CS; ++c)
        __builtin_nontemporal_store(a[c], &out[(size_t)c * P + p]);
}

// ---- Fallback (R2 kernel) if ws is too small -------------------------------
__global__ __launch_bounds__(256) void gs4d_fallback(
    const float* __restrict__ inp, const float* __restrict__ grid,
    float* __restrict__ out, int P)
{
    int p = blockIdx.x * 256 + threadIdx.x;
    if (p >= P) return;
    int c = blockIdx.y;
    float4 g = reinterpret_cast<const float4*>(grid)[p];
    float c0 = (g.x + 1.0f) * 0.5f * (XS - 1);
    float c1 = (g.y + 1.0f) * 0.5f * (YS - 1);
    float c2 = (g.z + 1.0f) * 0.5f * (US - 1);
    float c3 = (g.w + 1.0f) * 0.5f * (VS - 1);
    float f0 = floorf(c0), f1 = floorf(c1), f2 = floorf(c2), f3 = floorf(c3);
    int i0 = (int)f0, i1 = (int)f1, i2 = (int)f2, i3 = (int)f3;
    float t0 = c0 - f0, t1 = c1 - f1, t2 = c2 - f2, t3 = c3 - f3;
    float w0[2], w1[2], w2[2], w3[2];
    int   q0[2], q1[2], q2[2], q3[2];
    #pragma unroll
    for (int b = 0; b < 2; ++b) {
        int j;
        j = i0 + b; w0[b] = (b ? t0 : 1.0f - t0) * ((j >= 0 && j < XS) ? 1.0f : 0.0f); q0[b] = min(max(j, 0), XS - 1);
        j = i1 + b; w1[b] = (b ? t1 : 1.0f - t1) * ((j >= 0 && j < YS) ? 1.0f : 0.0f); q1[b] = min(max(j, 0), YS - 1);
        j = i2 + b; w2[b] = (b ? t2 : 1.0f - t2) * ((j >= 0 && j < US) ? 1.0f : 0.0f); q2[b] = min(max(j, 0), US - 1);
        j = i3 + b; w3[b] = (b ? t3 : 1.0f - t3) * ((j >= 0 && j < VS) ? 1.0f : 0.0f); q3[b] = min(max(j, 0), VS - 1);
    }
    const float* ip = inp + (size_t)c * CH_STRIDE;
    float acc = 0.0f;
    #pragma unroll
    for (int bx = 0; bx < 2; ++bx)
    #pragma unroll
    for (int by = 0; by < 2; ++by)
    #pragma unroll
    for (int bu = 0; bu < 2; ++bu)
    #pragma unroll
    for (int bv = 0; bv < 2; ++bv) {
        int idx = ((q0[bx] * YS + q1[by]) * US + q2[bu]) * VS + q3[bv];
        acc = fmaf(w0[bx] * w1[by] * w2[bu] * w3[bv], ip[idx], acc);
    }
    __builtin_nontemporal_store(acc, &out[(size_t)c * P + p]);
}
} // anonymous namespace

extern "C" void kernel_launch(void* const* d_in, const int* in_sizes, int n_in,
                              void* d_out, int out_size, void* d_ws, size_t ws_size,
                              hipStream_t stream) {
    const float* inp  = (const float*)d_in[0];   // [1,16,8,8,256,256] f32
    const float* grid = (const float*)d_in[1];   // [1,P,4] f32
    float* out = (float*)d_out;                  // [1,16,P] f32
    int P = in_sizes[1] / 4;
    int pblocks = (P + 255) / 256;

    if (ws_size >= SINGLE_BYTES) {
        __half* ws = (__half*)d_ws;
        transpose_h_kernel<<<CH_STRIDE / 256, 256, 0, stream>>>(inp, ws);
        gather_h_kernel<<<pblocks, 256, 0, stream>>>(ws, grid, out, P);
    } else {
        dim3 blocks(pblocks, CS);
        gs4d_fallback<<<blocks, 256, 0, stream>>>(inp, grid, out, P);
    }
}